// Round 1
// baseline (1991.074 us; speedup 1.0000x reference)
//
#include <hip/hip_runtime.h>
#include <math.h>

#define EMBED   256
#define M_HEADS 8
#define DVAL    32
#define LK      16
#define S_TOTAL 21760
#define NQ      8192
#define QB      8      // queries per block in the fused kernel
#define VROWS   32     // rows per block in v_proj

// ---------------------------------------------------------------------------
// Kernel 1: v_masked = value_mask * (value @ W_val + b_val)
// rows = N*S_TOTAL = 43520, cols = 256, K = 256. 32 rows per block.
// ---------------------------------------------------------------------------
__global__ __launch_bounds__(256) void vproj_kernel(
    const float* __restrict__ value,
    const float* __restrict__ vmask,
    const float* __restrict__ W_val,
    const float* __restrict__ b_val,
    float* __restrict__ v_out)
{
    __shared__ float sA[VROWS][EMBED];   // 32 KiB
    const int t = threadIdx.x;
    const int row0 = blockIdx.x * VROWS;

    // stage A tile (coalesced)
    #pragma unroll
    for (int i = 0; i < VROWS; ++i)
        sA[i][t] = value[(size_t)(row0 + i) * EMBED + t];
    __syncthreads();

    float acc[VROWS];
    #pragma unroll
    for (int r = 0; r < VROWS; ++r) acc[r] = 0.f;

    for (int k = 0; k < EMBED; k += 4) {
        const float w0 = W_val[(k + 0) * EMBED + t];
        const float w1 = W_val[(k + 1) * EMBED + t];
        const float w2 = W_val[(k + 2) * EMBED + t];
        const float w3 = W_val[(k + 3) * EMBED + t];
        #pragma unroll
        for (int r = 0; r < VROWS; ++r) {
            const float4 a = *(const float4*)&sA[r][k];
            acc[r] = fmaf(a.x, w0, acc[r]);
            acc[r] = fmaf(a.y, w1, acc[r]);
            acc[r] = fmaf(a.z, w2, acc[r]);
            acc[r] = fmaf(a.w, w3, acc[r]);
        }
    }

    const float bv = b_val[t];
    #pragma unroll
    for (int r = 0; r < VROWS; ++r) {
        const int row = row0 + r;
        v_out[(size_t)row * EMBED + t] = (acc[r] + bv) * vmask[row];
    }
}

// ---------------------------------------------------------------------------
// Kernel 2 (fused): per 8-query tile:
//   attn logits + offsets GEMMs -> softmax -> bilinear sampling -> W_out GEMM
// ---------------------------------------------------------------------------
__global__ __launch_bounds__(256) void msda_kernel(
    const float* __restrict__ queries,
    const float* __restrict__ qgl,
    const float* __restrict__ W_off,  const float* __restrict__ b_off,
    const float* __restrict__ W_attn, const float* __restrict__ b_attn,
    const float* __restrict__ W_out,  const float* __restrict__ b_out,
    const float* __restrict__ v_tab,
    float* __restrict__ out)
{
    __shared__ float s_qT[EMBED][QB];            // 8 KiB, transposed queries; reused as mid^T
    __shared__ float s_off[QB][EMBED];           // 8 KiB
    __shared__ float s_attn[QB][M_HEADS * LK];   // 4 KiB
    __shared__ float s_geom[QB][4];

    const int t   = threadIdx.x;
    const int blk = blockIdx.x;
    const int n   = blk >> 10;                 // 1024 blocks per batch (8192/8)
    const int q0  = (blk & 1023) * QB;
    const size_t qbase = ((size_t)n * NQ + q0) * EMBED;

    // stage transposed query tile
    #pragma unroll
    for (int qi = 0; qi < QB; ++qi)
        s_qT[t][qi] = queries[qbase + (size_t)qi * EMBED + t];

    // geometry (sigmoid) per query
    if (t < QB) {
        const float* g = &qgl[((size_t)n * NQ + q0 + t) * 4];
        const float sx = 1.f / (1.f + __expf(-g[0]));
        const float sy = 1.f / (1.f + __expf(-g[1]));
        const float sw = 1.f / (1.f + __expf(-g[2]));
        const float sh = 1.f / (1.f + __expf(-g[3]));
        s_geom[t][0] = sx;
        s_geom[t][1] = sy;
        s_geom[t][2] = sw * 0.125f;   // (1/K)*SCALE = 0.125
        s_geom[t][3] = sh * 0.125f;
    }
    __syncthreads();

    // ---- phase 1a: offsets col t (all 256 threads) ----
    {
        float acc[QB];
        #pragma unroll
        for (int qi = 0; qi < QB; ++qi) acc[qi] = 0.f;
        #pragma unroll 2
        for (int k = 0; k < EMBED; ++k) {
            const float w = W_off[k * EMBED + t];
            const float4 a0 = *(const float4*)&s_qT[k][0];
            const float4 a1 = *(const float4*)&s_qT[k][4];
            acc[0] = fmaf(a0.x, w, acc[0]);
            acc[1] = fmaf(a0.y, w, acc[1]);
            acc[2] = fmaf(a0.z, w, acc[2]);
            acc[3] = fmaf(a0.w, w, acc[3]);
            acc[4] = fmaf(a1.x, w, acc[4]);
            acc[5] = fmaf(a1.y, w, acc[5]);
            acc[6] = fmaf(a1.z, w, acc[6]);
            acc[7] = fmaf(a1.w, w, acc[7]);
        }
        const float b = b_off[t];
        #pragma unroll
        for (int qi = 0; qi < QB; ++qi) s_off[qi][t] = acc[qi] + b;
    }

    // ---- phase 1b: attention logits col t (t<128) ----
    if (t < M_HEADS * LK) {
        float acc[QB];
        #pragma unroll
        for (int qi = 0; qi < QB; ++qi) acc[qi] = 0.f;
        #pragma unroll 2
        for (int k = 0; k < EMBED; ++k) {
            const float w = W_attn[k * (M_HEADS * LK) + t];
            const float4 a0 = *(const float4*)&s_qT[k][0];
            const float4 a1 = *(const float4*)&s_qT[k][4];
            acc[0] = fmaf(a0.x, w, acc[0]);
            acc[1] = fmaf(a0.y, w, acc[1]);
            acc[2] = fmaf(a0.z, w, acc[2]);
            acc[3] = fmaf(a0.w, w, acc[3]);
            acc[4] = fmaf(a1.x, w, acc[4]);
            acc[5] = fmaf(a1.y, w, acc[5]);
            acc[6] = fmaf(a1.z, w, acc[6]);
            acc[7] = fmaf(a1.w, w, acc[7]);
        }
        const float b = b_attn[t];
        #pragma unroll
        for (int qi = 0; qi < QB; ++qi) s_attn[qi][t] = acc[qi] + b;
    }
    __syncthreads();

    // ---- softmax over LK per (query, head): 64 tasks ----
    if (t < QB * M_HEADS) {
        const int qi = t >> 3;
        const int m  = t & 7;
        float* a = &s_attn[qi][m * LK];
        float mx = a[0];
        #pragma unroll
        for (int i = 1; i < LK; ++i) mx = fmaxf(mx, a[i]);
        float s = 0.f;
        #pragma unroll
        for (int i = 0; i < LK; ++i) { const float e = __expf(a[i] - mx); a[i] = e; s += e; }
        const float inv = 1.f / s;
        #pragma unroll
        for (int i = 0; i < LK; ++i) a[i] *= inv;
    }
    __syncthreads();

    // ---- phase 2: bilinear sampling. thread = (head m, channel d) ----
    const int m = t >> 5;
    // channel in v table = m*32 + d = t
    const float* __restrict__ vb = v_tab + (size_t)n * S_TOTAL * EMBED;

    float acc[QB];
    #pragma unroll
    for (int qi = 0; qi < QB; ++qi) acc[qi] = 0.f;

    #pragma unroll
    for (int qi = 0; qi < QB; ++qi) {
        const float cx  = s_geom[qi][0];
        const float cy  = s_geom[qi][1];
        const float scx = s_geom[qi][2];
        const float scy = s_geom[qi][3];
        #pragma unroll
        for (int lk = 0; lk < LK; ++lk) {
            const int l  = lk >> 2;
            const int Wl = 128 >> l;
            const int Hl = 128 >> l;
            const int start = (l == 0) ? 0 : (l == 1) ? 16384 : (l == 2) ? 20480 : 21504;

            const float aw = s_attn[qi][m * LK + lk];
            const float dx = s_off[qi][(m * LK + lk) * 2 + 0];
            const float dy = s_off[qi][(m * LK + lk) * 2 + 1];
            const float px = cx + dx * scx;
            const float py = cy + dy * scy;
            const float gx = fminf(fmaxf(2.f * px - 1.f, -1.f), 1.f);
            const float gy = fminf(fmaxf(2.f * py - 1.f, -1.f), 1.f);
            const float x = (gx + 1.f) * (Wl * 0.5f) - 0.5f;
            const float y = (gy + 1.f) * (Hl * 0.5f) - 0.5f;
            const float x0f = floorf(x), y0f = floorf(y);
            const int   x0 = (int)x0f, y0 = (int)y0f;
            const float wx = x - x0f, wy = y - y0f;

            const float w00 = (1.f - wx) * (1.f - wy);
            const float w10 = wx * (1.f - wy);
            const float w01 = (1.f - wx) * wy;
            const float w11 = wx * wy;

            const float* base = vb + (size_t)start * EMBED;
            float s = 0.f;
            const bool vx0 = (x0 >= 0) & (x0 < Wl);
            const bool vx1 = (x0 + 1 >= 0) & (x0 + 1 < Wl);
            const bool vy0 = (y0 >= 0) & (y0 < Hl);
            const bool vy1 = (y0 + 1 >= 0) & (y0 + 1 < Hl);
            if (vx0 & vy0) s = fmaf(w00, base[(size_t)(y0 * Wl + x0) * EMBED + t], s);
            if (vx1 & vy0) s = fmaf(w10, base[(size_t)(y0 * Wl + x0 + 1) * EMBED + t], s);
            if (vx0 & vy1) s = fmaf(w01, base[(size_t)((y0 + 1) * Wl + x0) * EMBED + t], s);
            if (vx1 & vy1) s = fmaf(w11, base[(size_t)((y0 + 1) * Wl + x0 + 1) * EMBED + t], s);

            acc[qi] = fmaf(aw, s, acc[qi]);
        }
    }

    // ---- phase 3: fused output GEMM. reuse s_qT as mid^T ----
    #pragma unroll
    for (int qi = 0; qi < QB; ++qi) s_qT[t][qi] = acc[qi];
    __syncthreads();

    {
        float f[QB];
        #pragma unroll
        for (int qi = 0; qi < QB; ++qi) f[qi] = 0.f;
        #pragma unroll 2
        for (int k = 0; k < EMBED; ++k) {
            const float w = W_out[k * EMBED + t];
            const float4 a0 = *(const float4*)&s_qT[k][0];
            const float4 a1 = *(const float4*)&s_qT[k][4];
            f[0] = fmaf(a0.x, w, f[0]);
            f[1] = fmaf(a0.y, w, f[1]);
            f[2] = fmaf(a0.z, w, f[2]);
            f[3] = fmaf(a0.w, w, f[3]);
            f[4] = fmaf(a1.x, w, f[4]);
            f[5] = fmaf(a1.y, w, f[5]);
            f[6] = fmaf(a1.z, w, f[6]);
            f[7] = fmaf(a1.w, w, f[7]);
        }
        const float b = b_out[t];
        #pragma unroll
        for (int qi = 0; qi < QB; ++qi)
            out[qbase + (size_t)qi * EMBED + t] = f[qi] + b;
    }
}

// ---------------------------------------------------------------------------
extern "C" void kernel_launch(void* const* d_in, const int* in_sizes, int n_in,
                              void* d_out, int out_size, void* d_ws, size_t ws_size,
                              hipStream_t stream) {
    (void)in_sizes; (void)n_in; (void)out_size; (void)ws_size;

    const float* queries = (const float*)d_in[0];
    const float* qgl     = (const float*)d_in[1];
    const float* value   = (const float*)d_in[2];
    const float* vmask   = (const float*)d_in[3];
    const float* W_off   = (const float*)d_in[4];
    const float* b_off   = (const float*)d_in[5];
    const float* W_attn  = (const float*)d_in[6];
    const float* b_attn  = (const float*)d_in[7];
    const float* W_val   = (const float*)d_in[8];
    const float* b_val   = (const float*)d_in[9];
    const float* W_out   = (const float*)d_in[10];
    const float* b_out   = (const float*)d_in[11];

    float* v_ws = (float*)d_ws;                 // 2*21760*256 floats = 44.6 MB
    float* outp = (float*)d_out;

    const int n_rows = 2 * S_TOTAL;             // 43520
    vproj_kernel<<<n_rows / VROWS, 256, 0, stream>>>(value, vmask, W_val, b_val, v_ws);

    const int n_qblocks = 2 * NQ / QB;          // 2048
    msda_kernel<<<n_qblocks, 256, 0, stream>>>(queries, qgl,
                                               W_off, b_off, W_attn, b_attn,
                                               W_out, b_out, v_ws, outp);
}

// Round 2
// 539.220 us; speedup vs baseline: 3.6925x; 3.6925x over previous
//
#include <hip/hip_runtime.h>
#include <math.h>

#define EMBED   256
#define M_HEADS 8
#define DVAL    32
#define LK      16
#define S_TOTAL 21760
#define NQ      8192
#define QB      8      // queries per block (qproj / sample)
#define VROWS   32     // rows per block in v_proj / out gemm

// workspace layout (floats)
#define V_ELEMS   (2 * S_TOTAL * EMBED)          // 11,141,120 : per-head value table
#define PA_OFF    V_ELEMS
#define PA_ELEMS  (2 * NQ * 128 * 3)             //  6,291,456 : (x, y, attn) per point

// ---------------------------------------------------------------------------
// Kernel 1: v = value_mask * (value @ W_val + b_val), written per-head:
//           v_out[((n*M + m)*S_TOTAL + s)*32 + d],  m = t>>5, d = t&31
// ---------------------------------------------------------------------------
__global__ __launch_bounds__(256) void vproj_kernel(
    const float* __restrict__ value,
    const float* __restrict__ vmask,
    const float* __restrict__ W_val,
    const float* __restrict__ b_val,
    float* __restrict__ v_out)
{
    __shared__ float sA[VROWS][EMBED];   // 32 KiB
    const int t = threadIdx.x;
    const int row0 = blockIdx.x * VROWS;           // 21760 % 32 == 0: no batch straddle
    const int n  = row0 / S_TOTAL;
    const int s0 = row0 - n * S_TOTAL;

    #pragma unroll
    for (int i = 0; i < VROWS; ++i)
        sA[i][t] = value[(size_t)(row0 + i) * EMBED + t];
    __syncthreads();

    float acc[VROWS];
    #pragma unroll
    for (int r = 0; r < VROWS; ++r) acc[r] = 0.f;

    for (int k = 0; k < EMBED; k += 4) {
        const float w0 = W_val[(k + 0) * EMBED + t];
        const float w1 = W_val[(k + 1) * EMBED + t];
        const float w2 = W_val[(k + 2) * EMBED + t];
        const float w3 = W_val[(k + 3) * EMBED + t];
        #pragma unroll
        for (int r = 0; r < VROWS; ++r) {
            const float4 a = *(const float4*)&sA[r][k];
            acc[r] = fmaf(a.x, w0, acc[r]);
            acc[r] = fmaf(a.y, w1, acc[r]);
            acc[r] = fmaf(a.z, w2, acc[r]);
            acc[r] = fmaf(a.w, w3, acc[r]);
        }
    }

    const float bv = b_val[t];
    const int m = t >> 5, d = t & 31;
    const size_t hb = (size_t)(n * M_HEADS + m) * S_TOTAL;
    #pragma unroll
    for (int r = 0; r < VROWS; ++r) {
        const int s = s0 + r;
        v_out[(hb + s) * DVAL + d] = (acc[r] + bv) * vmask[row0 + r];
    }
}

// ---------------------------------------------------------------------------
// Kernel 2: per 8-query tile: offsets + attn GEMMs, softmax, position math.
// Writes pa[( (n*NQ+q)*128 + m*16+lk )*3] = {x_pix, y_pix, attn}
// ---------------------------------------------------------------------------
__global__ __launch_bounds__(256) void qproj_kernel(
    const float* __restrict__ queries,
    const float* __restrict__ qgl,
    const float* __restrict__ W_off,  const float* __restrict__ b_off,
    const float* __restrict__ W_attn, const float* __restrict__ b_attn,
    float* __restrict__ pa)
{
    __shared__ float s_qT[EMBED][QB];            // 8 KiB
    __shared__ float s_off[QB][EMBED];           // 8 KiB
    __shared__ float s_attn[QB][M_HEADS * LK];   // 4 KiB
    __shared__ float s_geom[QB][4];

    const int t   = threadIdx.x;
    const int blk = blockIdx.x;
    const int n   = blk >> 10;
    const int q0  = (blk & 1023) * QB;
    const size_t qbase = ((size_t)n * NQ + q0) * EMBED;

    #pragma unroll
    for (int qi = 0; qi < QB; ++qi)
        s_qT[t][qi] = queries[qbase + (size_t)qi * EMBED + t];

    if (t < QB) {
        const float* g = &qgl[((size_t)n * NQ + q0 + t) * 4];
        s_geom[t][0] = 1.f / (1.f + __expf(-g[0]));
        s_geom[t][1] = 1.f / (1.f + __expf(-g[1]));
        s_geom[t][2] = (1.f / (1.f + __expf(-g[2]))) * 0.125f;   // (1/K)*SCALE
        s_geom[t][3] = (1.f / (1.f + __expf(-g[3]))) * 0.125f;
    }
    __syncthreads();

    // offsets col t
    {
        float acc[QB];
        #pragma unroll
        for (int qi = 0; qi < QB; ++qi) acc[qi] = 0.f;
        #pragma unroll 2
        for (int k = 0; k < EMBED; ++k) {
            const float w = W_off[k * EMBED + t];
            const float4 a0 = *(const float4*)&s_qT[k][0];
            const float4 a1 = *(const float4*)&s_qT[k][4];
            acc[0] = fmaf(a0.x, w, acc[0]);
            acc[1] = fmaf(a0.y, w, acc[1]);
            acc[2] = fmaf(a0.z, w, acc[2]);
            acc[3] = fmaf(a0.w, w, acc[3]);
            acc[4] = fmaf(a1.x, w, acc[4]);
            acc[5] = fmaf(a1.y, w, acc[5]);
            acc[6] = fmaf(a1.z, w, acc[6]);
            acc[7] = fmaf(a1.w, w, acc[7]);
        }
        const float b = b_off[t];
        #pragma unroll
        for (int qi = 0; qi < QB; ++qi) s_off[qi][t] = acc[qi] + b;
    }

    // attn logits col t (t<128)
    if (t < M_HEADS * LK) {
        float acc[QB];
        #pragma unroll
        for (int qi = 0; qi < QB; ++qi) acc[qi] = 0.f;
        #pragma unroll 2
        for (int k = 0; k < EMBED; ++k) {
            const float w = W_attn[k * (M_HEADS * LK) + t];
            const float4 a0 = *(const float4*)&s_qT[k][0];
            const float4 a1 = *(const float4*)&s_qT[k][4];
            acc[0] = fmaf(a0.x, w, acc[0]);
            acc[1] = fmaf(a0.y, w, acc[1]);
            acc[2] = fmaf(a0.z, w, acc[2]);
            acc[3] = fmaf(a0.w, w, acc[3]);
            acc[4] = fmaf(a1.x, w, acc[4]);
            acc[5] = fmaf(a1.y, w, acc[5]);
            acc[6] = fmaf(a1.z, w, acc[6]);
            acc[7] = fmaf(a1.w, w, acc[7]);
        }
        const float b = b_attn[t];
        #pragma unroll
        for (int qi = 0; qi < QB; ++qi) s_attn[qi][t] = acc[qi] + b;
    }
    __syncthreads();

    // softmax over LK per (query, head)
    if (t < QB * M_HEADS) {
        const int qi = t >> 3, m = t & 7;
        float* a = &s_attn[qi][m * LK];
        float mx = a[0];
        #pragma unroll
        for (int i = 1; i < LK; ++i) mx = fmaxf(mx, a[i]);
        float s = 0.f;
        #pragma unroll
        for (int i = 0; i < LK; ++i) { const float e = __expf(a[i] - mx); a[i] = e; s += e; }
        const float inv = 1.f / s;
        #pragma unroll
        for (int i = 0; i < LK; ++i) a[i] *= inv;
    }
    __syncthreads();

    // position math -> pa triples
    if (t < 128) {
        const int lk = t & 15;
        const int l  = lk >> 2;
        const float Wl = (float)(128 >> l);
        #pragma unroll
        for (int qi = 0; qi < QB; ++qi) {
            const float px = fmaf(s_off[qi][2 * t + 0], s_geom[qi][2], s_geom[qi][0]);
            const float py = fmaf(s_off[qi][2 * t + 1], s_geom[qi][3], s_geom[qi][1]);
            const float gx = fminf(fmaxf(2.f * px - 1.f, -1.f), 1.f);
            const float gy = fminf(fmaxf(2.f * py - 1.f, -1.f), 1.f);
            const float x = (gx + 1.f) * (Wl * 0.5f) - 0.5f;
            const float y = (gy + 1.f) * (Wl * 0.5f) - 0.5f;
            const size_t idx = (((size_t)(n * NQ + q0 + qi)) * 128 + t) * 3;
            pa[idx + 0] = x;
            pa[idx + 1] = y;
            pa[idx + 2] = s_attn[qi][t];
        }
    }
}

// ---------------------------------------------------------------------------
// Kernel 3: bilinear sampling. block = (n, qchunk, m); m = blockIdx&7 so each
// XCD (round-robin by blockIdx%8) mostly re-reads ONE head's 2.8 MB slice.
// group g = t>>5 handles query q0+g; lane d = t&31 is the channel.
// Writes mid directly into d_out at [n*NQ+q][m*32+d].
// ---------------------------------------------------------------------------
__global__ __launch_bounds__(256) void sample_kernel(
    const float* __restrict__ pa,
    const float* __restrict__ v_tab,
    float* __restrict__ mid)
{
    __shared__ float s_pa[QB * LK * 3];          // 1.5 KiB

    const int t    = threadIdx.x;
    const int m    = blockIdx.x & 7;
    const int rest = blockIdx.x >> 3;
    const int qc   = rest & 1023;
    const int n    = rest >> 10;
    const int q0   = qc * QB;

    for (int idx = t; idx < QB * LK * 3; idx += 256) {
        const int qi = idx / 48;
        const int j  = idx - qi * 48;
        s_pa[idx] = pa[(((size_t)(n * NQ + q0 + qi)) * 128 + m * 16) * 3 + j];
    }
    __syncthreads();

    const int g = t >> 5;
    const int d = t & 31;
    const float* __restrict__ vb = v_tab + (size_t)(n * M_HEADS + m) * S_TOTAL * DVAL;

    float acc = 0.f;
    #pragma unroll
    for (int lk = 0; lk < LK; ++lk) {
        const int l     = lk >> 2;
        const int Wl    = 128 >> l;
        const int start = (l == 0) ? 0 : (l == 1) ? 16384 : (l == 2) ? 20480 : 21504;

        const float x  = s_pa[(g * LK + lk) * 3 + 0];
        const float y  = s_pa[(g * LK + lk) * 3 + 1];
        const float aw = s_pa[(g * LK + lk) * 3 + 2];

        const float x0f = floorf(x), y0f = floorf(y);
        const int   x0 = (int)x0f, y0 = (int)y0f;
        const float wx = x - x0f, wy = y - y0f;

        const float vx0 = (x0 >= 0) ? 1.f : 0.f;            // x0 <= Wl-1 always
        const float vx1 = (x0 + 1 <= Wl - 1) ? 1.f : 0.f;   // x0+1 >= 0 always
        const float vy0 = (y0 >= 0) ? 1.f : 0.f;
        const float vy1 = (y0 + 1 <= Wl - 1) ? 1.f : 0.f;

        const int xc0 = max(x0, 0);
        const int xc1 = min(x0 + 1, Wl - 1);
        const int yc0 = max(y0, 0);
        const int yc1 = min(y0 + 1, Wl - 1);

        const float w00 = aw * (1.f - wx) * (1.f - wy) * vx0 * vy0;
        const float w10 = aw * wx * (1.f - wy) * vx1 * vy0;
        const float w01 = aw * (1.f - wx) * wy * vx0 * vy1;
        const float w11 = aw * wx * wy * vx1 * vy1;

        const float* __restrict__ b = vb + (size_t)start * DVAL;
        acc = fmaf(w00, b[(size_t)(yc0 * Wl + xc0) * DVAL + d], acc);
        acc = fmaf(w10, b[(size_t)(yc0 * Wl + xc1) * DVAL + d], acc);
        acc = fmaf(w01, b[(size_t)(yc1 * Wl + xc0) * DVAL + d], acc);
        acc = fmaf(w11, b[(size_t)(yc1 * Wl + xc1) * DVAL + d], acc);
    }

    mid[((size_t)(n * NQ + q0 + g)) * EMBED + m * DVAL + d] = acc;
}

// ---------------------------------------------------------------------------
// Kernel 4: in-place out = mid @ W_out + b_out on d_out (32 rows per block;
// each block reads its own rows to LDS, barriers, overwrites the same rows).
// ---------------------------------------------------------------------------
__global__ __launch_bounds__(256) void out_kernel(
    const float* __restrict__ W_out,
    const float* __restrict__ b_out,
    float* __restrict__ io)
{
    __shared__ float sA[VROWS][EMBED];   // 32 KiB
    const int t = threadIdx.x;
    const int row0 = blockIdx.x * VROWS;

    #pragma unroll
    for (int i = 0; i < VROWS; ++i)
        sA[i][t] = io[(size_t)(row0 + i) * EMBED + t];
    __syncthreads();

    float acc[VROWS];
    #pragma unroll
    for (int r = 0; r < VROWS; ++r) acc[r] = 0.f;

    for (int k = 0; k < EMBED; k += 4) {
        const float w0 = W_out[(k + 0) * EMBED + t];
        const float w1 = W_out[(k + 1) * EMBED + t];
        const float w2 = W_out[(k + 2) * EMBED + t];
        const float w3 = W_out[(k + 3) * EMBED + t];
        #pragma unroll
        for (int r = 0; r < VROWS; ++r) {
            const float4 a = *(const float4*)&sA[r][k];
            acc[r] = fmaf(a.x, w0, acc[r]);
            acc[r] = fmaf(a.y, w1, acc[r]);
            acc[r] = fmaf(a.z, w2, acc[r]);
            acc[r] = fmaf(a.w, w3, acc[r]);
        }
    }

    const float b = b_out[t];
    #pragma unroll
    for (int r = 0; r < VROWS; ++r)
        io[(size_t)(row0 + r) * EMBED + t] = acc[r] + b;
}

// ---------------------------------------------------------------------------
extern "C" void kernel_launch(void* const* d_in, const int* in_sizes, int n_in,
                              void* d_out, int out_size, void* d_ws, size_t ws_size,
                              hipStream_t stream) {
    (void)in_sizes; (void)n_in; (void)out_size; (void)ws_size;

    const float* queries = (const float*)d_in[0];
    const float* qgl     = (const float*)d_in[1];
    const float* value   = (const float*)d_in[2];
    const float* vmask   = (const float*)d_in[3];
    const float* W_off   = (const float*)d_in[4];
    const float* b_off   = (const float*)d_in[5];
    const float* W_attn  = (const float*)d_in[6];
    const float* b_attn  = (const float*)d_in[7];
    const float* W_val   = (const float*)d_in[8];
    const float* b_val   = (const float*)d_in[9];
    const float* W_out   = (const float*)d_in[10];
    const float* b_out   = (const float*)d_in[11];

    float* v_ws  = (float*)d_ws;                  // 44.6 MB per-head value table
    float* pa_ws = (float*)d_ws + PA_OFF;         // 25.2 MB (x,y,attn) triples
    float* outp  = (float*)d_out;

    vproj_kernel<<<(2 * S_TOTAL) / VROWS, 256, 0, stream>>>(value, vmask, W_val, b_val, v_ws);
    qproj_kernel<<<2 * NQ / QB, 256, 0, stream>>>(queries, qgl, W_off, b_off,
                                                  W_attn, b_attn, pa_ws);
    sample_kernel<<<2 * (NQ / QB) * M_HEADS, 256, 0, stream>>>(pa_ws, v_ws, outp);
    out_kernel<<<(2 * NQ) / VROWS, 256, 0, stream>>>(W_out, b_out, outp);
}

// Round 3
// 470.634 us; speedup vs baseline: 4.2306x; 1.1457x over previous
//
#include <hip/hip_runtime.h>
#include <math.h>

#define EMBED   256
#define M_HEADS 8
#define DVAL    32
#define LK      16
#define S_TOTAL 21760
#define NQ      8192
#define QB      8      // queries per block (sample)
#define QBQ     32     // queries per block (qproj)

typedef __attribute__((ext_vector_type(8))) short s16x8;
typedef __attribute__((ext_vector_type(4))) float f32x4;

// fp32 -> bf16 (RNE), bit-pattern as short
__device__ __forceinline__ short f2bf(float f) {
    unsigned u = __float_as_uint(f);
    u += 0x7fffu + ((u >> 16) & 1u);
    return (short)(u >> 16);
}

// workspace layout (float offsets)
#define V_ELEMS   (2 * S_TOTAL * EMBED)          // 11,141,120 : per-head value table
#define PA_OFF    V_ELEMS
#define PA_ELEMS  (2 * NQ * 128 * 3)             //  6,291,456 : (x, y, attn) per point
#define WVPK_OFF  (PA_OFF + PA_ELEMS)            // 32,768 floats (65,536 bf16)
#define WOPK_OFF  (WVPK_OFF + 32768)

// ---------------------------------------------------------------------------
// Pack W[k][c] (K=256 x C cols, fp32) into MFMA B-fragment order (bf16):
//   Wpk[((kt*C + c)*4 + q)*8 + j] = bf16(W[kt*32 + q*8 + j][c])
// so lane (n=l&15, q=l>>4) reads 16 contiguous bytes per (kt, n-tile).
// ---------------------------------------------------------------------------
__global__ __launch_bounds__(256) void pack_w_kernel(
    const float* __restrict__ W, short* __restrict__ Wpk, int C)
{
    const int t = threadIdx.x;
    if (t >= C) return;
    for (int k = 0; k < 256; ++k) {
        const int kt = k >> 5, q = (k >> 3) & 3, j = k & 7;
        Wpk[(((kt * C + t) << 2) + q) * 8 + j] = f2bf(W[k * C + t]);
    }
}

// ---------------------------------------------------------------------------
// Kernel 1 (MFMA): v = value_mask * (value @ W_val + b_val), per-head layout
//   v_out[((n*M + m)*S_TOTAL + s)*32 + d]
// Block: 4 waves, each wave owns 32 unique rows; 64 cols per block. No LDS.
// grid = (4 col-groups, 340 row-groups of 128)
// ---------------------------------------------------------------------------
__global__ __launch_bounds__(256) void vproj_kernel(
    const float* __restrict__ value,
    const float* __restrict__ vmask,
    const short* __restrict__ Wpk,
    const float* __restrict__ b_val,
    float* __restrict__ v_out)
{
    const int t  = threadIdx.x;
    const int w  = t >> 6, l = t & 63;
    const int m  = l & 15, qd = l >> 4;
    const int r0 = blockIdx.y * 128 + w * 32;
    const int c0 = blockIdx.x * 64;

    f32x4 acc[2][4] = {};

    for (int kt = 0; kt < 8; ++kt) {
        s16x8 a[2], b[4];
        #pragma unroll
        for (int mt = 0; mt < 2; ++mt) {
            const float* ap = value + (size_t)(r0 + mt * 16 + m) * EMBED + kt * 32 + qd * 8;
            const float4 a0 = *(const float4*)ap;
            const float4 a1 = *(const float4*)(ap + 4);
            a[mt] = (s16x8){ f2bf(a0.x), f2bf(a0.y), f2bf(a0.z), f2bf(a0.w),
                             f2bf(a1.x), f2bf(a1.y), f2bf(a1.z), f2bf(a1.w) };
        }
        #pragma unroll
        for (int nt = 0; nt < 4; ++nt) {
            const int col = c0 + nt * 16 + m;
            b[nt] = *(const s16x8*)(Wpk + (((kt * 256 + col) << 2) + qd) * 8);
        }
        #pragma unroll
        for (int mt = 0; mt < 2; ++mt)
            #pragma unroll
            for (int nt = 0; nt < 4; ++nt)
                acc[mt][nt] = __builtin_amdgcn_mfma_f32_16x16x32_bf16(a[mt], b[nt], acc[mt][nt], 0, 0, 0);
    }

    #pragma unroll
    for (int mt = 0; mt < 2; ++mt) {
        #pragma unroll
        for (int r = 0; r < 4; ++r) {
            const int grow = r0 + mt * 16 + qd * 4 + r;
            const int n = (grow >= S_TOTAL) ? 1 : 0;
            const int s = grow - n * S_TOTAL;
            const float mk = vmask[grow];
            #pragma unroll
            for (int nt = 0; nt < 4; ++nt) {
                const int col = c0 + nt * 16 + m;
                const int hm = col >> 5, d = col & 31;
                v_out[((size_t)(n * M_HEADS + hm) * S_TOTAL + s) * DVAL + d] =
                    (acc[mt][nt][r] + b_val[col]) * mk;
            }
        }
    }
}

// ---------------------------------------------------------------------------
// Kernel 2: 32 queries per block: offsets + attn GEMMs (fp32), softmax,
// position math. Writes pa[((n*NQ+q)*128 + m*16+lk)*3] = {x_pix, y_pix, attn}
// ---------------------------------------------------------------------------
__global__ __launch_bounds__(256) void qproj_kernel(
    const float* __restrict__ queries,
    const float* __restrict__ qgl,
    const float* __restrict__ W_off,  const float* __restrict__ b_off,
    const float* __restrict__ W_attn, const float* __restrict__ b_attn,
    float* __restrict__ pa)
{
    __shared__ float s_q[EMBED][36];       // [k][q], padded; reused as s_off[32][256]
    __shared__ float s_attn[QBQ][129];
    __shared__ float s_geom[QBQ][4];

    const int t  = threadIdx.x;
    const int n  = blockIdx.x >> 8;        // 256 blocks per batch
    const int q0 = (blockIdx.x & 255) * QBQ;

    // stage q^T: thread = (qi = t&31, k0 = (t>>5)*4), 8 passes over k
    {
        const int qi = t & 31;
        #pragma unroll
        for (int pass = 0; pass < 8; ++pass) {
            const int k0 = ((t >> 5) + pass * 8) * 4;
            const float4 v = *(const float4*)&queries[((size_t)(n * NQ + q0 + qi)) * EMBED + k0];
            s_q[k0 + 0][qi] = v.x;
            s_q[k0 + 1][qi] = v.y;
            s_q[k0 + 2][qi] = v.z;
            s_q[k0 + 3][qi] = v.w;
        }
    }
    if (t < QBQ) {
        const float* g = &qgl[((size_t)(n * NQ + q0 + t)) * 4];
        s_geom[t][0] = 1.f / (1.f + __expf(-g[0]));
        s_geom[t][1] = 1.f / (1.f + __expf(-g[1]));
        s_geom[t][2] = (1.f / (1.f + __expf(-g[2]))) * 0.125f;
        s_geom[t][3] = (1.f / (1.f + __expf(-g[3]))) * 0.125f;
    }
    __syncthreads();

    // phase A: offsets col t (256 cols), 32 accumulators
    float accA[QBQ];
    #pragma unroll
    for (int qi = 0; qi < QBQ; ++qi) accA[qi] = 0.f;
    for (int k = 0; k < EMBED; ++k) {
        const float wv = W_off[k * EMBED + t];
        #pragma unroll
        for (int qq = 0; qq < 8; ++qq) {
            const float4 a = *(const float4*)&s_q[k][qq * 4];
            accA[qq * 4 + 0] = fmaf(a.x, wv, accA[qq * 4 + 0]);
            accA[qq * 4 + 1] = fmaf(a.y, wv, accA[qq * 4 + 1]);
            accA[qq * 4 + 2] = fmaf(a.z, wv, accA[qq * 4 + 2]);
            accA[qq * 4 + 3] = fmaf(a.w, wv, accA[qq * 4 + 3]);
        }
    }

    // phase B: attn col t (t<128), 32 accumulators
    float accB[QBQ];
    #pragma unroll
    for (int qi = 0; qi < QBQ; ++qi) accB[qi] = 0.f;
    if (t < M_HEADS * LK) {
        for (int k = 0; k < EMBED; ++k) {
            const float wv = W_attn[k * (M_HEADS * LK) + t];
            #pragma unroll
            for (int qq = 0; qq < 8; ++qq) {
                const float4 a = *(const float4*)&s_q[k][qq * 4];
                accB[qq * 4 + 0] = fmaf(a.x, wv, accB[qq * 4 + 0]);
                accB[qq * 4 + 1] = fmaf(a.y, wv, accB[qq * 4 + 1]);
                accB[qq * 4 + 2] = fmaf(a.z, wv, accB[qq * 4 + 2]);
                accB[qq * 4 + 3] = fmaf(a.w, wv, accB[qq * 4 + 3]);
            }
        }
    }
    __syncthreads();   // all reads of s_q done; safe to overwrite

    float* s_off = &s_q[0][0];             // [qi*256 + col], 8192 floats fits 9216
    {
        const float bo = b_off[t];
        #pragma unroll
        for (int qi = 0; qi < QBQ; ++qi) s_off[qi * EMBED + t] = accA[qi] + bo;
    }
    if (t < M_HEADS * LK) {
        const float ba = b_attn[t];
        #pragma unroll
        for (int qi = 0; qi < QBQ; ++qi) s_attn[qi][t] = accB[qi] + ba;
    }
    __syncthreads();

    // softmax over LK per (query, head): 32*8 = 256 tasks
    {
        const int qi = t >> 3, hm = t & 7;
        float* a = &s_attn[qi][hm * LK];
        float mx = a[0];
        #pragma unroll
        for (int i = 1; i < LK; ++i) mx = fmaxf(mx, a[i]);
        float s = 0.f;
        #pragma unroll
        for (int i = 0; i < LK; ++i) { const float e = __expf(a[i] - mx); a[i] = e; s += e; }
        const float inv = 1.f / s;
        #pragma unroll
        for (int i = 0; i < LK; ++i) a[i] *= inv;
    }
    __syncthreads();

    // position math -> pa triples (32 q x 128 points = 4096, 16 per thread)
    for (int p = t; p < QBQ * 128; p += 256) {
        const int qi = p >> 7;
        const int pt = p & 127;
        const int lk = pt & 15;
        const int lvl = lk >> 2;
        const float Wl = (float)(128 >> lvl);
        const float px = fmaf(s_off[qi * EMBED + 2 * pt + 0], s_geom[qi][2], s_geom[qi][0]);
        const float py = fmaf(s_off[qi * EMBED + 2 * pt + 1], s_geom[qi][3], s_geom[qi][1]);
        const float gx = fminf(fmaxf(2.f * px - 1.f, -1.f), 1.f);
        const float gy = fminf(fmaxf(2.f * py - 1.f, -1.f), 1.f);
        const float x = (gx + 1.f) * (Wl * 0.5f) - 0.5f;
        const float y = (gy + 1.f) * (Wl * 0.5f) - 0.5f;
        const size_t idx = (((size_t)(n * NQ + q0 + qi)) * 128 + pt) * 3;
        pa[idx + 0] = x;
        pa[idx + 1] = y;
        pa[idx + 2] = s_attn[qi][pt];
    }
}

// ---------------------------------------------------------------------------
// Kernel 3: bilinear sampling (unchanged). block = (n, qchunk, m); m=blk&7 for
// XCD L2 locality. Writes mid (fp32) directly into d_out.
// ---------------------------------------------------------------------------
__global__ __launch_bounds__(256) void sample_kernel(
    const float* __restrict__ pa,
    const float* __restrict__ v_tab,
    float* __restrict__ mid)
{
    __shared__ float s_pa[QB * LK * 3];

    const int t    = threadIdx.x;
    const int m    = blockIdx.x & 7;
    const int rest = blockIdx.x >> 3;
    const int qc   = rest & 1023;
    const int n    = rest >> 10;
    const int q0   = qc * QB;

    for (int idx = t; idx < QB * LK * 3; idx += 256) {
        const int qi = idx / 48;
        const int j  = idx - qi * 48;
        s_pa[idx] = pa[(((size_t)(n * NQ + q0 + qi)) * 128 + m * 16) * 3 + j];
    }
    __syncthreads();

    const int g = t >> 5;
    const int d = t & 31;
    const float* __restrict__ vb = v_tab + (size_t)(n * M_HEADS + m) * S_TOTAL * DVAL;

    float acc = 0.f;
    #pragma unroll
    for (int lk = 0; lk < LK; ++lk) {
        const int l     = lk >> 2;
        const int Wl    = 128 >> l;
        const int start = (l == 0) ? 0 : (l == 1) ? 16384 : (l == 2) ? 20480 : 21504;

        const float x  = s_pa[(g * LK + lk) * 3 + 0];
        const float y  = s_pa[(g * LK + lk) * 3 + 1];
        const float aw = s_pa[(g * LK + lk) * 3 + 2];

        const float x0f = floorf(x), y0f = floorf(y);
        const int   x0 = (int)x0f, y0 = (int)y0f;
        const float wx = x - x0f, wy = y - y0f;

        const float vx0 = (x0 >= 0) ? 1.f : 0.f;
        const float vx1 = (x0 + 1 <= Wl - 1) ? 1.f : 0.f;
        const float vy0 = (y0 >= 0) ? 1.f : 0.f;
        const float vy1 = (y0 + 1 <= Wl - 1) ? 1.f : 0.f;

        const int xc0 = max(x0, 0);
        const int xc1 = min(x0 + 1, Wl - 1);
        const int yc0 = max(y0, 0);
        const int yc1 = min(y0 + 1, Wl - 1);

        const float w00 = aw * (1.f - wx) * (1.f - wy) * vx0 * vy0;
        const float w10 = aw * wx * (1.f - wy) * vx1 * vy0;
        const float w01 = aw * (1.f - wx) * wy * vx0 * vy1;
        const float w11 = aw * wx * wy * vx1 * vy1;

        const float* __restrict__ b = vb + (size_t)start * DVAL;
        acc = fmaf(w00, b[(size_t)(yc0 * Wl + xc0) * DVAL + d], acc);
        acc = fmaf(w10, b[(size_t)(yc0 * Wl + xc1) * DVAL + d], acc);
        acc = fmaf(w01, b[(size_t)(yc1 * Wl + xc0) * DVAL + d], acc);
        acc = fmaf(w11, b[(size_t)(yc1 * Wl + xc1) * DVAL + d], acc);
    }

    mid[((size_t)(n * NQ + q0 + g)) * EMBED + m * DVAL + d] = acc;
}

// ---------------------------------------------------------------------------
// Kernel 4 (MFMA, in-place on d_out): out = mid @ W_out + b_out.
// Block stages its own 64 rows (fp32 -> bf16) into LDS, then 4 waves x 64 cols.
// In-place safe: all global reads complete before the barrier; writes after.
// ---------------------------------------------------------------------------
__global__ __launch_bounds__(256) void out_kernel(
    const short* __restrict__ Wpk,
    const float* __restrict__ b_out,
    float* __restrict__ io)
{
    __shared__ short sA[64][264];          // 33 KiB, +8 pad keeps 16B align + bank spread

    const int t    = threadIdx.x;
    const int w    = t >> 6, l = t & 63;
    const int m    = l & 15, qd = l >> 4;
    const int row0 = blockIdx.x * 64;
    const int c0   = w * 64;

    // stage 64 rows x 256 cols fp32 -> bf16 (coalesced float4 reads)
    for (int idx = t; idx < 64 * 64; idx += 256) {
        const int row = idx >> 6;
        const int c4  = idx & 63;
        const float4 v = *(const float4*)&io[(size_t)(row0 + row) * EMBED + c4 * 4];
        short4 s;
        s.x = f2bf(v.x); s.y = f2bf(v.y); s.z = f2bf(v.z); s.w = f2bf(v.w);
        *(short4*)&sA[row][c4 * 4] = s;
    }
    __syncthreads();

    f32x4 acc[4][4] = {};
    for (int kt = 0; kt < 8; ++kt) {
        s16x8 a[4], b[4];
        #pragma unroll
        for (int mt = 0; mt < 4; ++mt)
            a[mt] = *(const s16x8*)&sA[mt * 16 + m][kt * 32 + qd * 8];
        #pragma unroll
        for (int nt = 0; nt < 4; ++nt) {
            const int col = c0 + nt * 16 + m;
            b[nt] = *(const s16x8*)(Wpk + (((kt * 256 + col) << 2) + qd) * 8);
        }
        #pragma unroll
        for (int mt = 0; mt < 4; ++mt)
            #pragma unroll
            for (int nt = 0; nt < 4; ++nt)
                acc[mt][nt] = __builtin_amdgcn_mfma_f32_16x16x32_bf16(a[mt], b[nt], acc[mt][nt], 0, 0, 0);
    }

    #pragma unroll
    for (int mt = 0; mt < 4; ++mt) {
        #pragma unroll
        for (int r = 0; r < 4; ++r) {
            const int row = row0 + mt * 16 + qd * 4 + r;
            #pragma unroll
            for (int nt = 0; nt < 4; ++nt) {
                const int col = c0 + nt * 16 + m;
                io[(size_t)row * EMBED + col] = acc[mt][nt][r] + b_out[col];
            }
        }
    }
}

// ---------------------------------------------------------------------------
extern "C" void kernel_launch(void* const* d_in, const int* in_sizes, int n_in,
                              void* d_out, int out_size, void* d_ws, size_t ws_size,
                              hipStream_t stream) {
    (void)in_sizes; (void)n_in; (void)out_size; (void)ws_size;

    const float* queries = (const float*)d_in[0];
    const float* qgl     = (const float*)d_in[1];
    const float* value   = (const float*)d_in[2];
    const float* vmask   = (const float*)d_in[3];
    const float* W_off   = (const float*)d_in[4];
    const float* b_off   = (const float*)d_in[5];
    const float* W_attn  = (const float*)d_in[6];
    const float* b_attn  = (const float*)d_in[7];
    const float* W_val   = (const float*)d_in[8];
    const float* b_val   = (const float*)d_in[9];
    const float* W_out   = (const float*)d_in[10];
    const float* b_out   = (const float*)d_in[11];

    float* ws    = (float*)d_ws;
    float* v_ws  = ws;                          // 44.6 MB per-head value table
    float* pa_ws = ws + PA_OFF;                 // 25.2 MB (x,y,attn) triples
    short* wvpk  = (short*)(ws + WVPK_OFF);     // 128 KB bf16 packed W_val
    short* wopk  = (short*)(ws + WOPK_OFF);     // 128 KB bf16 packed W_out
    float* outp  = (float*)d_out;

    pack_w_kernel<<<1, 256, 0, stream>>>(W_val, wvpk, 256);
    pack_w_kernel<<<1, 256, 0, stream>>>(W_out, wopk, 256);

    vproj_kernel<<<dim3(4, 340), 256, 0, stream>>>(value, vmask, wvpk, b_val, v_ws);
    qproj_kernel<<<2 * NQ / QBQ, 256, 0, stream>>>(queries, qgl, W_off, b_off,
                                                   W_attn, b_attn, pa_ws);
    sample_kernel<<<2 * (NQ / QB) * M_HEADS, 256, 0, stream>>>(pa_ws, v_ws, outp);
    out_kernel<<<(2 * NQ) / 64, 256, 0, stream>>>(wopk, b_out, outp);
}

// Round 4
// 425.028 us; speedup vs baseline: 4.6846x; 1.1073x over previous
//
#include <hip/hip_runtime.h>
#include <math.h>

#define EMBED   256
#define M_HEADS 8
#define DVAL    32
#define LK      16
#define S_TOTAL 21760
#define NQ      8192
#define QB      8
#define NROWS   (2 * NQ)          // 16384 total query rows

typedef __attribute__((ext_vector_type(8))) short s16x8;
typedef __attribute__((ext_vector_type(4))) float f32x4;
typedef unsigned short u16;

__device__ __forceinline__ short f2bf(float f) {
    unsigned u = __float_as_uint(f);
    u += 0x7fffu + ((u >> 16) & 1u);
    return (short)(u >> 16);
}
__device__ __forceinline__ float bf2f(short h) {
    return __uint_as_float(((unsigned)(u16)h) << 16);
}

// ---------------- workspace layout (float offsets) ----------------
#define V_OFF     0                      // value table, bf16: 11,141,120 shorts
#define V_FLTS    5570560
#define PA_OFF    (V_OFF + V_FLTS)       // (x,y,attn) fp32 triples
#define PA_FLTS   6291456
#define QHI_OFF   (PA_OFF + PA_FLTS)     // query hi-plane bf16 [16384][256]
#define QPL_FLTS  2097152
#define QLO_OFF   (QHI_OFF + QPL_FLTS)   // query lo-plane
#define MID_OFF   (QLO_OFF + QPL_FLTS)   // mid bf16 [16384][256]
#define MID_FLTS  2097152
#define WHI_OFF   (MID_OFF + MID_FLTS)   // packed [W_off|W_attn] hi, C=384
#define WOA_FLTS  49152
#define WLO_OFF   (WHI_OFF + WOA_FLTS)
#define WV_OFF    (WLO_OFF + WOA_FLTS)   // packed W_val bf16, C=256
#define WO_OFF    (WV_OFF + 32768)       // packed W_out bf16, C=256

// ---------------------------------------------------------------------------
// Pre-split queries fp32 -> (hi, lo) bf16 planes. grid 4096 x 256, float4/thr.
// ---------------------------------------------------------------------------
__global__ __launch_bounds__(256) void presplit_kernel(
    const float* __restrict__ q, u16* __restrict__ qh, u16* __restrict__ ql)
{
    const int i4 = blockIdx.x * 256 + threadIdx.x;
    const float4 v = ((const float4*)q)[i4];
    short4 h, l;
    h.x = f2bf(v.x); l.x = f2bf(v.x - bf2f(h.x));
    h.y = f2bf(v.y); l.y = f2bf(v.y - bf2f(h.y));
    h.z = f2bf(v.z); l.z = f2bf(v.z - bf2f(h.z));
    h.w = f2bf(v.w); l.w = f2bf(v.w - bf2f(h.w));
    ((short4*)qh)[i4] = h;
    ((short4*)ql)[i4] = l;
}

// ---------------------------------------------------------------------------
// Pack W[k][c] (256 x C fp32) into MFMA B-fragment order, single bf16:
//   Wpk[((kt*C + c)*4 + q)*8 + j] = bf16(W[kt*32 + q*8 + j][c])
// ---------------------------------------------------------------------------
__global__ __launch_bounds__(256) void pack_w_kernel(
    const float* __restrict__ W, u16* __restrict__ Wpk, int C)
{
    const int t = threadIdx.x;
    if (t >= C) return;
    for (int k = 0; k < 256; ++k) {
        const int kt = k >> 5, q = (k >> 3) & 3, j = k & 7;
        Wpk[(((kt * C + t) << 2) + q) * 8 + j] = (u16)f2bf(W[k * C + t]);
    }
}

// ---------------------------------------------------------------------------
// Pack combined [W_off(256) | W_attn(128)] -> hi/lo bf16 fragments, C=384.
// ---------------------------------------------------------------------------
__global__ __launch_bounds__(256) void pack_w_split_kernel(
    const float* __restrict__ W_off, const float* __restrict__ W_attn,
    u16* __restrict__ Whi, u16* __restrict__ Wlo)
{
    const int c = blockIdx.x * 256 + threadIdx.x;
    if (c >= 384) return;
    for (int k = 0; k < 256; ++k) {
        const float f = (c < 256) ? W_off[k * 256 + c] : W_attn[k * 128 + (c - 256)];
        const short h = f2bf(f);
        const short lo = f2bf(f - bf2f(h));
        const int kt = k >> 5, q = (k >> 3) & 3, j = k & 7;
        const int idx = (((kt * 384 + c) << 2) + q) * 8 + j;
        Whi[idx] = (u16)h;
        Wlo[idx] = (u16)lo;
    }
}

// ---------------------------------------------------------------------------
// Kernel 1 (MFMA): v = mask * (value @ W_val + b_val), per-head bf16 layout
//   v_out[((n*M + m)*S_TOTAL + s)*32 + d]. grid (4 colgroups, 340 rowgroups)
// ---------------------------------------------------------------------------
__global__ __launch_bounds__(256) void vproj_kernel(
    const float* __restrict__ value,
    const float* __restrict__ vmask,
    const u16* __restrict__ Wpk,
    const float* __restrict__ b_val,
    u16* __restrict__ v_out)
{
    const int t  = threadIdx.x;
    const int w  = t >> 6, l = t & 63;
    const int c  = l & 15, qd = l >> 4;
    const int r0 = blockIdx.y * 128 + w * 32;
    const int c0 = blockIdx.x * 64;

    f32x4 acc[2][4] = {};

    for (int kt = 0; kt < 8; ++kt) {
        s16x8 a[2], b[4];
        #pragma unroll
        for (int mt = 0; mt < 2; ++mt) {
            const float* ap = value + (size_t)(r0 + mt * 16 + c) * EMBED + kt * 32 + qd * 8;
            const float4 a0 = *(const float4*)ap;
            const float4 a1 = *(const float4*)(ap + 4);
            a[mt] = (s16x8){ f2bf(a0.x), f2bf(a0.y), f2bf(a0.z), f2bf(a0.w),
                             f2bf(a1.x), f2bf(a1.y), f2bf(a1.z), f2bf(a1.w) };
        }
        #pragma unroll
        for (int nt = 0; nt < 4; ++nt)
            b[nt] = *(const s16x8*)(Wpk + (((kt * 256 + c0 + nt * 16 + c) << 2) + qd) * 8);
        #pragma unroll
        for (int mt = 0; mt < 2; ++mt)
            #pragma unroll
            for (int nt = 0; nt < 4; ++nt)
                acc[mt][nt] = __builtin_amdgcn_mfma_f32_16x16x32_bf16(a[mt], b[nt], acc[mt][nt], 0, 0, 0);
    }

    #pragma unroll
    for (int mt = 0; mt < 2; ++mt) {
        #pragma unroll
        for (int r = 0; r < 4; ++r) {
            const int grow = r0 + mt * 16 + qd * 4 + r;
            const int n = (grow >= S_TOTAL) ? 1 : 0;
            const int s = grow - n * S_TOTAL;
            const float mk = vmask[grow];
            #pragma unroll
            for (int nt = 0; nt < 4; ++nt) {
                const int col = c0 + nt * 16 + c;
                const int hm = col >> 5, d = col & 31;
                v_out[((size_t)(n * M_HEADS + hm) * S_TOTAL + s) * DVAL + d] =
                    (u16)f2bf((acc[mt][nt][r] + b_val[col]) * mk);
            }
        }
    }
}

// ---------------------------------------------------------------------------
// Kernel 2 (split-bf16 MFMA): [offsets | attn] = q @ [W_off|W_attn] + bias
// via 3-pass hi/lo MFMA (~fp32-accurate). 32 query rows per block, 384 cols,
// 4 waves x 96 cols. A-frags direct from global bf16 planes (L1-resident).
// Epilogue: softmax over 16 pts/head + position math -> pa triples.
// ---------------------------------------------------------------------------
__global__ __launch_bounds__(256) void qproj_kernel(
    const u16* __restrict__ q_hi, const u16* __restrict__ q_lo,
    const float* __restrict__ qgl,
    const u16* __restrict__ Whi, const u16* __restrict__ Wlo,
    const float* __restrict__ b_off, const float* __restrict__ b_attn,
    float* __restrict__ pa)
{
    __shared__ float s_off[32][260];    // 33.3 KiB
    __shared__ float s_attn[32][132];   // 16.9 KiB
    __shared__ float s_geom[32][4];

    const int t  = threadIdx.x;
    const int w  = t >> 6, l = t & 63;
    const int c  = l & 15, qd = l >> 4;
    const int row0 = blockIdx.x * 32;   // flat row = n*NQ + q
    const int c0 = w * 96;

    if (t < 32) {
        const float* g = &qgl[(size_t)(row0 + t) * 4];
        s_geom[t][0] = 1.f / (1.f + __expf(-g[0]));
        s_geom[t][1] = 1.f / (1.f + __expf(-g[1]));
        s_geom[t][2] = (1.f / (1.f + __expf(-g[2]))) * 0.125f;
        s_geom[t][3] = (1.f / (1.f + __expf(-g[3]))) * 0.125f;
    }

    f32x4 acc[2][6] = {};

    for (int kt = 0; kt < 8; ++kt) {
        s16x8 ah[2], al[2], bh[6], bl[6];
        #pragma unroll
        for (int mt = 0; mt < 2; ++mt) {
            const size_t ao = (size_t)(row0 + mt * 16 + c) * EMBED + kt * 32 + qd * 8;
            ah[mt] = *(const s16x8*)(q_hi + ao);
            al[mt] = *(const s16x8*)(q_lo + ao);
        }
        #pragma unroll
        for (int nt = 0; nt < 6; ++nt) {
            const int idx = (((kt * 384 + c0 + nt * 16 + c) << 2) + qd) * 8;
            bh[nt] = *(const s16x8*)(Whi + idx);
            bl[nt] = *(const s16x8*)(Wlo + idx);
        }
        #pragma unroll
        for (int mt = 0; mt < 2; ++mt)
            #pragma unroll
            for (int nt = 0; nt < 6; ++nt) {
                acc[mt][nt] = __builtin_amdgcn_mfma_f32_16x16x32_bf16(ah[mt], bh[nt], acc[mt][nt], 0, 0, 0);
                acc[mt][nt] = __builtin_amdgcn_mfma_f32_16x16x32_bf16(ah[mt], bl[nt], acc[mt][nt], 0, 0, 0);
                acc[mt][nt] = __builtin_amdgcn_mfma_f32_16x16x32_bf16(al[mt], bh[nt], acc[mt][nt], 0, 0, 0);
            }
    }

    // C -> LDS (+bias). col side is uniform per (wave, nt) since 256 % 16 == 0.
    #pragma unroll
    for (int mt = 0; mt < 2; ++mt)
        #pragma unroll
        for (int nt = 0; nt < 6; ++nt) {
            const int col = c0 + nt * 16 + c;
            #pragma unroll
            for (int r = 0; r < 4; ++r) {
                const int row = mt * 16 + qd * 4 + r;
                if (col < 256) s_off[row][col] = acc[mt][nt][r] + b_off[col];
                else           s_attn[row][col - 256] = acc[mt][nt][r] + b_attn[col - 256];
            }
        }
    __syncthreads();

    // softmax over LK per (query, head): 32*8 = 256 tasks
    {
        const int qi = t >> 3, hm = t & 7;
        float* a = &s_attn[qi][hm * LK];
        float mx = a[0];
        #pragma unroll
        for (int i = 1; i < LK; ++i) mx = fmaxf(mx, a[i]);
        float s = 0.f;
        #pragma unroll
        for (int i = 0; i < LK; ++i) { const float e = __expf(a[i] - mx); a[i] = e; s += e; }
        const float inv = 1.f / s;
        #pragma unroll
        for (int i = 0; i < LK; ++i) a[i] *= inv;
    }
    __syncthreads();

    // position math -> pa triples (32 q x 128 pts, 16 per thread)
    for (int p = t; p < 32 * 128; p += 256) {
        const int qi = p >> 7;
        const int pt = p & 127;
        const int lvl = (pt & 15) >> 2;
        const float Wl = (float)(128 >> lvl);
        const float px = fmaf(s_off[qi][2 * pt + 0], s_geom[qi][2], s_geom[qi][0]);
        const float py = fmaf(s_off[qi][2 * pt + 1], s_geom[qi][3], s_geom[qi][1]);
        const float gx = fminf(fmaxf(2.f * px - 1.f, -1.f), 1.f);
        const float gy = fminf(fmaxf(2.f * py - 1.f, -1.f), 1.f);
        const float x = (gx + 1.f) * (Wl * 0.5f) - 0.5f;
        const float y = (gy + 1.f) * (Wl * 0.5f) - 0.5f;
        const size_t idx = ((size_t)(row0 + qi) * 128 + pt) * 3;
        pa[idx + 0] = x;
        pa[idx + 1] = y;
        pa[idx + 2] = s_attn[qi][pt];
    }
}

// ---------------------------------------------------------------------------
// Kernel 3: bilinear sampling on bf16 table. block = (n, qchunk, m); m=blk&7
// for XCD L2 locality. Writes bf16 mid to workspace.
// ---------------------------------------------------------------------------
__global__ __launch_bounds__(256) void sample_kernel(
    const float* __restrict__ pa,
    const u16* __restrict__ v_tab,
    u16* __restrict__ mid)
{
    __shared__ float s_pa[QB * LK * 3];

    const int t    = threadIdx.x;
    const int m    = blockIdx.x & 7;
    const int rest = blockIdx.x >> 3;
    const int qc   = rest & 1023;
    const int n    = rest >> 10;
    const int q0   = qc * QB;

    for (int idx = t; idx < QB * LK * 3; idx += 256) {
        const int qi = idx / 48;
        const int j  = idx - qi * 48;
        s_pa[idx] = pa[(((size_t)(n * NQ + q0 + qi)) * 128 + m * 16) * 3 + j];
    }
    __syncthreads();

    const int g = t >> 5;
    const int d = t & 31;
    const u16* __restrict__ vb = v_tab + (size_t)(n * M_HEADS + m) * S_TOTAL * DVAL;

    float acc = 0.f;
    #pragma unroll
    for (int lk = 0; lk < LK; ++lk) {
        const int l     = lk >> 2;
        const int Wl    = 128 >> l;
        const int start = (l == 0) ? 0 : (l == 1) ? 16384 : (l == 2) ? 20480 : 21504;

        const float x  = s_pa[(g * LK + lk) * 3 + 0];
        const float y  = s_pa[(g * LK + lk) * 3 + 1];
        const float aw = s_pa[(g * LK + lk) * 3 + 2];

        const float x0f = floorf(x), y0f = floorf(y);
        const int   x0 = (int)x0f, y0 = (int)y0f;
        const float wx = x - x0f, wy = y - y0f;

        const float vx0 = (x0 >= 0) ? 1.f : 0.f;
        const float vx1 = (x0 + 1 <= Wl - 1) ? 1.f : 0.f;
        const float vy0 = (y0 >= 0) ? 1.f : 0.f;
        const float vy1 = (y0 + 1 <= Wl - 1) ? 1.f : 0.f;

        const int xc0 = max(x0, 0);
        const int xc1 = min(x0 + 1, Wl - 1);
        const int yc0 = max(y0, 0);
        const int yc1 = min(y0 + 1, Wl - 1);

        const float w00 = aw * (1.f - wx) * (1.f - wy) * vx0 * vy0;
        const float w10 = aw * wx * (1.f - wy) * vx1 * vy0;
        const float w01 = aw * (1.f - wx) * wy * vx0 * vy1;
        const float w11 = aw * wx * wy * vx1 * vy1;

        const u16* __restrict__ b = vb + (size_t)start * DVAL;
        acc = fmaf(w00, bf2f((short)b[(yc0 * Wl + xc0) * DVAL + d]), acc);
        acc = fmaf(w10, bf2f((short)b[(yc0 * Wl + xc1) * DVAL + d]), acc);
        acc = fmaf(w01, bf2f((short)b[(yc1 * Wl + xc0) * DVAL + d]), acc);
        acc = fmaf(w11, bf2f((short)b[(yc1 * Wl + xc1) * DVAL + d]), acc);
    }

    mid[((size_t)(n * NQ + q0 + g)) * EMBED + m * DVAL + d] = (u16)f2bf(acc);
}

// ---------------------------------------------------------------------------
// Kernel 4 (MFMA, LDS-free): out = mid @ W_out + b_out. A-frags direct from
// bf16 mid plane. grid (4 colgroups, 128 rowgroups).
// ---------------------------------------------------------------------------
__global__ __launch_bounds__(256) void out_kernel(
    const u16* __restrict__ mid,
    const u16* __restrict__ Wpk,
    const float* __restrict__ b_out,
    float* __restrict__ out)
{
    const int t  = threadIdx.x;
    const int w  = t >> 6, l = t & 63;
    const int c  = l & 15, qd = l >> 4;
    const int r0 = blockIdx.y * 128 + w * 32;
    const int c0 = blockIdx.x * 64;

    f32x4 acc[2][4] = {};

    for (int kt = 0; kt < 8; ++kt) {
        s16x8 a[2], b[4];
        #pragma unroll
        for (int mt = 0; mt < 2; ++mt)
            a[mt] = *(const s16x8*)(mid + (size_t)(r0 + mt * 16 + c) * EMBED + kt * 32 + qd * 8);
        #pragma unroll
        for (int nt = 0; nt < 4; ++nt)
            b[nt] = *(const s16x8*)(Wpk + (((kt * 256 + c0 + nt * 16 + c) << 2) + qd) * 8);
        #pragma unroll
        for (int mt = 0; mt < 2; ++mt)
            #pragma unroll
            for (int nt = 0; nt < 4; ++nt)
                acc[mt][nt] = __builtin_amdgcn_mfma_f32_16x16x32_bf16(a[mt], b[nt], acc[mt][nt], 0, 0, 0);
    }

    #pragma unroll
    for (int mt = 0; mt < 2; ++mt)
        #pragma unroll
        for (int r = 0; r < 4; ++r) {
            const int row = r0 + mt * 16 + qd * 4 + r;
            #pragma unroll
            for (int nt = 0; nt < 4; ++nt) {
                const int col = c0 + nt * 16 + c;
                out[(size_t)row * EMBED + col] = acc[mt][nt][r] + b_out[col];
            }
        }
}

// ---------------------------------------------------------------------------
extern "C" void kernel_launch(void* const* d_in, const int* in_sizes, int n_in,
                              void* d_out, int out_size, void* d_ws, size_t ws_size,
                              hipStream_t stream) {
    (void)in_sizes; (void)n_in; (void)out_size; (void)ws_size;

    const float* queries = (const float*)d_in[0];
    const float* qgl     = (const float*)d_in[1];
    const float* value   = (const float*)d_in[2];
    const float* vmask   = (const float*)d_in[3];
    const float* W_off   = (const float*)d_in[4];
    const float* b_off   = (const float*)d_in[5];
    const float* W_attn  = (const float*)d_in[6];
    const float* b_attn  = (const float*)d_in[7];
    const float* W_val   = (const float*)d_in[8];
    const float* b_val   = (const float*)d_in[9];
    const float* W_out   = (const float*)d_in[10];
    const float* b_out   = (const float*)d_in[11];

    float* ws   = (float*)d_ws;
    u16*  v_ws  = (u16*)(ws + V_OFF);
    float* pa   = ws + PA_OFF;
    u16*  q_hi  = (u16*)(ws + QHI_OFF);
    u16*  q_lo  = (u16*)(ws + QLO_OFF);
    u16*  mid   = (u16*)(ws + MID_OFF);
    u16*  whi   = (u16*)(ws + WHI_OFF);
    u16*  wlo   = (u16*)(ws + WLO_OFF);
    u16*  wvpk  = (u16*)(ws + WV_OFF);
    u16*  wopk  = (u16*)(ws + WO_OFF);
    float* outp = (float*)d_out;

    presplit_kernel<<<NROWS * EMBED / 4 / 256, 256, 0, stream>>>(queries, q_hi, q_lo);
    pack_w_split_kernel<<<2, 256, 0, stream>>>(W_off, W_attn, whi, wlo);
    pack_w_kernel<<<1, 256, 0, stream>>>(W_val, wvpk, 256);
    pack_w_kernel<<<1, 256, 0, stream>>>(W_out, wopk, 256);

    vproj_kernel<<<dim3(4, 340), 256, 0, stream>>>(value, vmask, wvpk, b_val, v_ws);
    qproj_kernel<<<NROWS / 32, 256, 0, stream>>>(q_hi, q_lo, qgl, whi, wlo,
                                                 b_off, b_attn, pa);
    sample_kernel<<<2 * (NQ / QB) * M_HEADS, 256, 0, stream>>>(pa, v_ws, mid);
    out_kernel<<<dim3(4, 128), 256, 0, stream>>>(mid, wopk, b_out, outp);
}

// Round 5
// 220.963 us; speedup vs baseline: 9.0109x; 1.9235x over previous
//
#include <hip/hip_runtime.h>
#include <math.h>

#define EMBED   256
#define M_HEADS 8
#define DVAL    32
#define LK      16
#define S_TOTAL 21760
#define NQ      8192
#define NROWS   (2 * NQ)          // 16384 total query rows
#define QBS     16                // queries per block (sample)

typedef __attribute__((ext_vector_type(8))) short s16x8;
typedef __attribute__((ext_vector_type(4))) float f32x4;
typedef unsigned short u16;
typedef unsigned int   u32;

__device__ __forceinline__ short f2bf(float f) {
    unsigned u = __float_as_uint(f);
    u += 0x7fffu + ((u >> 16) & 1u);
    return (short)(u >> 16);
}
__device__ __forceinline__ float bf2f(short h) {
    return __uint_as_float(((unsigned)(u16)h) << 16);
}

// ---------------- workspace layout (float offsets) ----------------
#define V_OFF     0                      // value table, bf16: 11,141,120 shorts
#define V_FLTS    5570560
#define PA_OFF    (V_OFF + V_FLTS)       // (x,y,attn) fp32 triples
#define PA_FLTS   6291456
#define QHI_OFF   (PA_OFF + PA_FLTS)     // query hi-plane bf16 [16384][256]
#define QPL_FLTS  2097152
#define QLO_OFF   (QHI_OFF + QPL_FLTS)   // query lo-plane
#define MID_OFF   (QLO_OFF + QPL_FLTS)   // mid bf16 [16384][256]
#define MID_FLTS  2097152
#define WHI_OFF   (MID_OFF + MID_FLTS)   // packed [W_off|W_attn] hi, C=384
#define WOA_FLTS  49152
#define WLO_OFF   (WHI_OFF + WOA_FLTS)
#define WV_OFF    (WLO_OFF + WOA_FLTS)   // packed W_val bf16, C=256
#define WO_OFF    (WV_OFF + 32768)       // packed W_out bf16, C=256

// ---------------------------------------------------------------------------
// prep_kernel: fused presplit (blocks 0..4095) + W_val pack (4096..4351) +
// W_out pack (4352..4607) + [W_off|W_attn] hi/lo pack (4608..4991).
// ---------------------------------------------------------------------------
__global__ __launch_bounds__(256) void prep_kernel(
    const float* __restrict__ q,     u16* __restrict__ qh, u16* __restrict__ ql,
    const float* __restrict__ W_off, const float* __restrict__ W_attn,
    u16* __restrict__ Whi,           u16* __restrict__ Wlo,
    const float* __restrict__ W_val, u16* __restrict__ Wv,
    const float* __restrict__ W_out, u16* __restrict__ Wo)
{
    const int b = blockIdx.x;
    const int t = threadIdx.x;

    if (b < 4096) {                       // presplit queries -> hi/lo bf16
        const int i4 = b * 256 + t;
        const float4 v = ((const float4*)q)[i4];
        short4 h, l;
        h.x = f2bf(v.x); l.x = f2bf(v.x - bf2f(h.x));
        h.y = f2bf(v.y); l.y = f2bf(v.y - bf2f(h.y));
        h.z = f2bf(v.z); l.z = f2bf(v.z - bf2f(h.z));
        h.w = f2bf(v.w); l.w = f2bf(v.w - bf2f(h.w));
        ((short4*)qh)[i4] = h;
        ((short4*)ql)[i4] = l;
    } else if (b < 4096 + 512) {          // pack W_val / W_out (C=256)
        const int flat = (b - 4096) * 256 + t;       // 0..131071
        const int which = flat >> 16;                // 0: W_val, 1: W_out
        const int e = flat & 65535;
        const int k = e >> 8, c = e & 255;
        const float f = which ? W_out[k * 256 + c] : W_val[k * 256 + c];
        const int kt = k >> 5, qd = (k >> 3) & 3, j = k & 7;
        const int idx = (((kt * 256 + c) << 2) + qd) * 8 + j;
        (which ? Wo : Wv)[idx] = (u16)f2bf(f);
    } else {                              // pack [W_off|W_attn] hi/lo (C=384)
        const int flat = (b - 4608) * 256 + t;       // 0..98303
        const int k = flat / 384, c = flat - k * 384;
        const float f = (c < 256) ? W_off[k * 256 + c] : W_attn[k * 128 + (c - 256)];
        const short h = f2bf(f);
        const short lo = f2bf(f - bf2f(h));
        const int kt = k >> 5, qd = (k >> 3) & 3, j = k & 7;
        const int idx = (((kt * 384 + c) << 2) + qd) * 8 + j;
        Whi[idx] = (u16)h;
        Wlo[idx] = (u16)lo;
    }
}

// ---------------------------------------------------------------------------
// Kernel 1 (MFMA): v = mask * (value @ W_val + b_val), per-head bf16 layout
//   v_out[((n*M + m)*S_TOTAL + s)*32 + d]. grid (4 colgroups, 340 rowgroups)
// ---------------------------------------------------------------------------
__global__ __launch_bounds__(256) void vproj_kernel(
    const float* __restrict__ value,
    const float* __restrict__ vmask,
    const u16* __restrict__ Wpk,
    const float* __restrict__ b_val,
    u16* __restrict__ v_out)
{
    const int t  = threadIdx.x;
    const int w  = t >> 6, l = t & 63;
    const int c  = l & 15, qd = l >> 4;
    const int r0 = blockIdx.y * 128 + w * 32;
    const int c0 = blockIdx.x * 64;

    f32x4 acc[2][4] = {};

    for (int kt = 0; kt < 8; ++kt) {
        s16x8 a[2], b[4];
        #pragma unroll
        for (int mt = 0; mt < 2; ++mt) {
            const float* ap = value + (size_t)(r0 + mt * 16 + c) * EMBED + kt * 32 + qd * 8;
            const float4 a0 = *(const float4*)ap;
            const float4 a1 = *(const float4*)(ap + 4);
            a[mt] = (s16x8){ f2bf(a0.x), f2bf(a0.y), f2bf(a0.z), f2bf(a0.w),
                             f2bf(a1.x), f2bf(a1.y), f2bf(a1.z), f2bf(a1.w) };
        }
        #pragma unroll
        for (int nt = 0; nt < 4; ++nt)
            b[nt] = *(const s16x8*)(Wpk + (((kt * 256 + c0 + nt * 16 + c) << 2) + qd) * 8);
        #pragma unroll
        for (int mt = 0; mt < 2; ++mt)
            #pragma unroll
            for (int nt = 0; nt < 4; ++nt)
                acc[mt][nt] = __builtin_amdgcn_mfma_f32_16x16x32_bf16(a[mt], b[nt], acc[mt][nt], 0, 0, 0);
    }

    #pragma unroll
    for (int mt = 0; mt < 2; ++mt) {
        #pragma unroll
        for (int r = 0; r < 4; ++r) {
            const int grow = r0 + mt * 16 + qd * 4 + r;
            const int n = (grow >= S_TOTAL) ? 1 : 0;
            const int s = grow - n * S_TOTAL;
            const float mk = vmask[grow];
            #pragma unroll
            for (int nt = 0; nt < 4; ++nt) {
                const int col = c0 + nt * 16 + c;
                const int hm = col >> 5, d = col & 31;
                v_out[((size_t)(n * M_HEADS + hm) * S_TOTAL + s) * DVAL + d] =
                    (u16)f2bf((acc[mt][nt][r] + b_val[col]) * mk);
            }
        }
    }
}

// ---------------------------------------------------------------------------
// Kernel 2 (split-bf16 MFMA): [offsets | attn] = q @ [W_off|W_attn] + bias
// via 3-pass hi/lo MFMA. 32 query rows per block, 384 cols, 4 waves x 96.
// Epilogue: softmax + position math -> pa triples.
// ---------------------------------------------------------------------------
__global__ __launch_bounds__(256) void qproj_kernel(
    const u16* __restrict__ q_hi, const u16* __restrict__ q_lo,
    const float* __restrict__ qgl,
    const u16* __restrict__ Whi, const u16* __restrict__ Wlo,
    const float* __restrict__ b_off, const float* __restrict__ b_attn,
    float* __restrict__ pa)
{
    __shared__ float s_off[32][260];
    __shared__ float s_attn[32][132];
    __shared__ float s_geom[32][4];

    const int t  = threadIdx.x;
    const int w  = t >> 6, l = t & 63;
    const int c  = l & 15, qd = l >> 4;
    const int row0 = blockIdx.x * 32;
    const int c0 = w * 96;

    if (t < 32) {
        const float* g = &qgl[(size_t)(row0 + t) * 4];
        s_geom[t][0] = 1.f / (1.f + __expf(-g[0]));
        s_geom[t][1] = 1.f / (1.f + __expf(-g[1]));
        s_geom[t][2] = (1.f / (1.f + __expf(-g[2]))) * 0.125f;
        s_geom[t][3] = (1.f / (1.f + __expf(-g[3]))) * 0.125f;
    }

    f32x4 acc[2][6] = {};

    for (int kt = 0; kt < 8; ++kt) {
        s16x8 ah[2], al[2], bh[6], bl[6];
        #pragma unroll
        for (int mt = 0; mt < 2; ++mt) {
            const size_t ao = (size_t)(row0 + mt * 16 + c) * EMBED + kt * 32 + qd * 8;
            ah[mt] = *(const s16x8*)(q_hi + ao);
            al[mt] = *(const s16x8*)(q_lo + ao);
        }
        #pragma unroll
        for (int nt = 0; nt < 6; ++nt) {
            const int idx = (((kt * 384 + c0 + nt * 16 + c) << 2) + qd) * 8;
            bh[nt] = *(const s16x8*)(Whi + idx);
            bl[nt] = *(const s16x8*)(Wlo + idx);
        }
        #pragma unroll
        for (int mt = 0; mt < 2; ++mt)
            #pragma unroll
            for (int nt = 0; nt < 6; ++nt) {
                acc[mt][nt] = __builtin_amdgcn_mfma_f32_16x16x32_bf16(ah[mt], bh[nt], acc[mt][nt], 0, 0, 0);
                acc[mt][nt] = __builtin_amdgcn_mfma_f32_16x16x32_bf16(ah[mt], bl[nt], acc[mt][nt], 0, 0, 0);
                acc[mt][nt] = __builtin_amdgcn_mfma_f32_16x16x32_bf16(al[mt], bh[nt], acc[mt][nt], 0, 0, 0);
            }
    }

    #pragma unroll
    for (int mt = 0; mt < 2; ++mt)
        #pragma unroll
        for (int nt = 0; nt < 6; ++nt) {
            const int col = c0 + nt * 16 + c;
            #pragma unroll
            for (int r = 0; r < 4; ++r) {
                const int row = mt * 16 + qd * 4 + r;
                if (col < 256) s_off[row][col] = acc[mt][nt][r] + b_off[col];
                else           s_attn[row][col - 256] = acc[mt][nt][r] + b_attn[col - 256];
            }
        }
    __syncthreads();

    {
        const int qi = t >> 3, hm = t & 7;
        float* a = &s_attn[qi][hm * LK];
        float mx = a[0];
        #pragma unroll
        for (int i = 1; i < LK; ++i) mx = fmaxf(mx, a[i]);
        float s = 0.f;
        #pragma unroll
        for (int i = 0; i < LK; ++i) { const float e = __expf(a[i] - mx); a[i] = e; s += e; }
        const float inv = 1.f / s;
        #pragma unroll
        for (int i = 0; i < LK; ++i) a[i] *= inv;
    }
    __syncthreads();

    for (int p = t; p < 32 * 128; p += 256) {
        const int qi = p >> 7;
        const int pt = p & 127;
        const int lvl = (pt & 15) >> 2;
        const float Wl = (float)(128 >> lvl);
        const float px = fmaf(s_off[qi][2 * pt + 0], s_geom[qi][2], s_geom[qi][0]);
        const float py = fmaf(s_off[qi][2 * pt + 1], s_geom[qi][3], s_geom[qi][1]);
        const float gx = fminf(fmaxf(2.f * px - 1.f, -1.f), 1.f);
        const float gy = fminf(fmaxf(2.f * py - 1.f, -1.f), 1.f);
        const float x = (gx + 1.f) * (Wl * 0.5f) - 0.5f;
        const float y = (gy + 1.f) * (Wl * 0.5f) - 0.5f;
        const size_t idx = ((size_t)(row0 + qi) * 128 + pt) * 3;
        pa[idx + 0] = x;
        pa[idx + 1] = y;
        pa[idx + 2] = s_attn[qi][pt];
    }
}

// ---------------------------------------------------------------------------
// Kernel 3: bilinear sampling, restructured.
// Setup: 256 pts/block (16 q x 16 pts), one thread each -> LDS int4 offsets
// (clamped, level-base folded, *DVAL) + float4 weights (attn folded, OOB=0).
// Main: lane = (g = t>>4 query, dp = t&15 channel pair); 4-byte gathers pull
// 2 bf16 channels; per-point math amortized across all 32 channels.
// m = blk&7 keeps one head's slice L2-local per XCD.
// ---------------------------------------------------------------------------
__global__ __launch_bounds__(256) void sample_kernel(
    const float* __restrict__ pa,
    const u16* __restrict__ v_tab,
    u16* __restrict__ mid)
{
    __shared__ int4   s_idx[QBS * 17];   // stride 17: conflict-free b128 reads
    __shared__ float4 s_w[QBS * 17];

    const int t    = threadIdx.x;
    const int m    = blockIdx.x & 7;
    const int rest = blockIdx.x >> 3;
    const int qc   = rest & 511;
    const int n    = rest >> 9;
    const int q0   = qc * QBS;

    // ---- setup: one point per thread ----
    {
        const int qi = t >> 4, lk = t & 15;
        const int lvl   = lk >> 2;
        const int Wl    = 128 >> lvl;
        const int start = (lvl == 0) ? 0 : (lvl == 1) ? 16384 : (lvl == 2) ? 20480 : 21504;

        const size_t prow = ((size_t)(n * NQ + q0 + qi)) * 128 + m * 16 + lk;
        const float x  = pa[prow * 3 + 0];
        const float y  = pa[prow * 3 + 1];
        const float aw = pa[prow * 3 + 2];

        const float x0f = floorf(x), y0f = floorf(y);
        const int   x0 = (int)x0f, y0 = (int)y0f;
        const float wx = x - x0f, wy = y - y0f;

        const float vx0 = (x0 >= 0) ? 1.f : 0.f;
        const float vx1 = (x0 + 1 <= Wl - 1) ? 1.f : 0.f;
        const float vy0 = (y0 >= 0) ? 1.f : 0.f;
        const float vy1 = (y0 + 1 <= Wl - 1) ? 1.f : 0.f;

        const int xc0 = max(x0, 0);
        const int xc1 = min(x0 + 1, Wl - 1);
        const int yc0 = max(y0, 0);
        const int yc1 = min(y0 + 1, Wl - 1);

        const int e = qi * 17 + lk;
        s_idx[e] = make_int4((start + yc0 * Wl + xc0) * DVAL,
                             (start + yc0 * Wl + xc1) * DVAL,
                             (start + yc1 * Wl + xc0) * DVAL,
                             (start + yc1 * Wl + xc1) * DVAL);
        s_w[e] = make_float4(aw * (1.f - wx) * (1.f - wy) * vx0 * vy0,
                             aw * wx * (1.f - wy) * vx1 * vy0,
                             aw * (1.f - wx) * wy * vx0 * vy1,
                             aw * wx * wy * vx1 * vy1);
    }
    __syncthreads();

    // ---- gather: 2 channels per lane ----
    const int g = t >> 4, dp = t & 15;
    const u16* __restrict__ vbp =
        v_tab + (size_t)(n * M_HEADS + m) * S_TOTAL * DVAL + 2 * dp;

    float acc0 = 0.f, acc1 = 0.f;
    #pragma unroll
    for (int lk = 0; lk < LK; ++lk) {
        const int4   id = s_idx[g * 17 + lk];
        const float4 w  = s_w[g * 17 + lk];
        const u32 u0 = *(const u32*)(vbp + id.x);
        const u32 u1 = *(const u32*)(vbp + id.y);
        const u32 u2 = *(const u32*)(vbp + id.z);
        const u32 u3 = *(const u32*)(vbp + id.w);
        acc0 = fmaf(w.x, __uint_as_float(u0 << 16), acc0);
        acc1 = fmaf(w.x, __uint_as_float(u0 & 0xffff0000u), acc1);
        acc0 = fmaf(w.y, __uint_as_float(u1 << 16), acc0);
        acc1 = fmaf(w.y, __uint_as_float(u1 & 0xffff0000u), acc1);
        acc0 = fmaf(w.z, __uint_as_float(u2 << 16), acc0);
        acc1 = fmaf(w.z, __uint_as_float(u2 & 0xffff0000u), acc1);
        acc0 = fmaf(w.w, __uint_as_float(u3 << 16), acc0);
        acc1 = fmaf(w.w, __uint_as_float(u3 & 0xffff0000u), acc1);
    }

    const u32 packed = ((u32)(u16)f2bf(acc1) << 16) | (u32)(u16)f2bf(acc0);
    *(u32*)(mid + ((size_t)(n * NQ + q0 + g)) * EMBED + m * DVAL + 2 * dp) = packed;
}

// ---------------------------------------------------------------------------
// Kernel 4 (MFMA, LDS-free): out = mid @ W_out + b_out.
// ---------------------------------------------------------------------------
__global__ __launch_bounds__(256) void out_kernel(
    const u16* __restrict__ mid,
    const u16* __restrict__ Wpk,
    const float* __restrict__ b_out,
    float* __restrict__ out)
{
    const int t  = threadIdx.x;
    const int w  = t >> 6, l = t & 63;
    const int c  = l & 15, qd = l >> 4;
    const int r0 = blockIdx.y * 128 + w * 32;
    const int c0 = blockIdx.x * 64;

    f32x4 acc[2][4] = {};

    for (int kt = 0; kt < 8; ++kt) {
        s16x8 a[2], b[4];
        #pragma unroll
        for (int mt = 0; mt < 2; ++mt)
            a[mt] = *(const s16x8*)(mid + (size_t)(r0 + mt * 16 + c) * EMBED + kt * 32 + qd * 8);
        #pragma unroll
        for (int nt = 0; nt < 4; ++nt)
            b[nt] = *(const s16x8*)(Wpk + (((kt * 256 + c0 + nt * 16 + c) << 2) + qd) * 8);
        #pragma unroll
        for (int mt = 0; mt < 2; ++mt)
            #pragma unroll
            for (int nt = 0; nt < 4; ++nt)
                acc[mt][nt] = __builtin_amdgcn_mfma_f32_16x16x32_bf16(a[mt], b[nt], acc[mt][nt], 0, 0, 0);
    }

    #pragma unroll
    for (int mt = 0; mt < 2; ++mt)
        #pragma unroll
        for (int r = 0; r < 4; ++r) {
            const int row = r0 + mt * 16 + qd * 4 + r;
            #pragma unroll
            for (int nt = 0; nt < 4; ++nt) {
                const int col = c0 + nt * 16 + c;
                out[(size_t)row * EMBED + col] = acc[mt][nt][r] + b_out[col];
            }
        }
}

// ---------------------------------------------------------------------------
extern "C" void kernel_launch(void* const* d_in, const int* in_sizes, int n_in,
                              void* d_out, int out_size, void* d_ws, size_t ws_size,
                              hipStream_t stream) {
    (void)in_sizes; (void)n_in; (void)out_size; (void)ws_size;

    const float* queries = (const float*)d_in[0];
    const float* qgl     = (const float*)d_in[1];
    const float* value   = (const float*)d_in[2];
    const float* vmask   = (const float*)d_in[3];
    const float* W_off   = (const float*)d_in[4];
    const float* b_off   = (const float*)d_in[5];
    const float* W_attn  = (const float*)d_in[6];
    const float* b_attn  = (const float*)d_in[7];
    const float* W_val   = (const float*)d_in[8];
    const float* b_val   = (const float*)d_in[9];
    const float* W_out   = (const float*)d_in[10];
    const float* b_out   = (const float*)d_in[11];

    float* ws   = (float*)d_ws;
    u16*  v_ws  = (u16*)(ws + V_OFF);
    float* pa   = ws + PA_OFF;
    u16*  q_hi  = (u16*)(ws + QHI_OFF);
    u16*  q_lo  = (u16*)(ws + QLO_OFF);
    u16*  mid   = (u16*)(ws + MID_OFF);
    u16*  whi   = (u16*)(ws + WHI_OFF);
    u16*  wlo   = (u16*)(ws + WLO_OFF);
    u16*  wvpk  = (u16*)(ws + WV_OFF);
    u16*  wopk  = (u16*)(ws + WO_OFF);
    float* outp = (float*)d_out;

    prep_kernel<<<4992, 256, 0, stream>>>(queries, q_hi, q_lo,
                                          W_off, W_attn, whi, wlo,
                                          W_val, wvpk, W_out, wopk);

    vproj_kernel<<<dim3(4, 340), 256, 0, stream>>>(value, vmask, wvpk, b_val, v_ws);
    qproj_kernel<<<NROWS / 32, 256, 0, stream>>>(q_hi, q_lo, qgl, whi, wlo,
                                                 b_off, b_attn, pa);
    sample_kernel<<<2 * (NQ / QBS) * M_HEADS, 256, 0, stream>>>(pa, v_ws, mid);
    out_kernel<<<dim3(4, 128), 256, 0, stream>>>(mid, wopk, b_out, outp);
}